// Round 16
// baseline (412.622 us; speedup 1.0000x reference)
//
#include <hip/hip_runtime.h>

// AffinityPropagate (CSPN): B=8, C=32, H=W=256, K=3, prop_time=16.
// R15: occupancy fix for the streaming pipeline. CPB 4->2: ring 48->24 KB
// (6 blocks/CU LDS-cap), grid 512->1024 (4 blocks/CU resident), VGPR stays
// in (64,128] band => occupancy cap 50% (was grid-capped at ~21%).
// Prefetches (weights row q+1, x row q+2) issued at TOP of the front loop
// for max load->use distance (R14 validated the mechanism). Pad dropped
// (R14 proved it does nothing to the conflict counter).

#define B_ 8
#define C_ 32
#define H_ 256
#define W_ 256
#define T_ 4
#define CPB 2
#define CHUNK 32
#define NFRONT (CHUNK + 3 * (T_ - 1))   // 41 fronts

// Planar weights: wts[((b*9)+j)*H*W + h*W + w]
__global__ __launch_bounds__(256)
void prep_weights_kernel(const float* __restrict__ guided,
                         const float* __restrict__ depth,
                         float* __restrict__ wts,
                         int total /* B*H*W */) {
    int idx = blockIdx.x * 256 + threadIdx.x;
    if (idx >= total) return;
    int b  = idx >> 16;        // H*W = 65536
    int hw = idx & 0xFFFF;
    const float* gp = guided + (((size_t)b * 8) << 16) + hw;
    float g[8];
    float m = -3.4e38f;
#pragma unroll
    for (int j = 0; j < 8; j++) { g[j] = gp[(size_t)j << 16]; m = fmaxf(m, g[j]); }
    float s = 0.f;
#pragma unroll
    for (int j = 0; j < 8; j++) { g[j] = expf(g[j] - m); s += g[j]; }
    float inv = 1.0f / s;
    float d = depth[(((size_t)b) << 16) + hw];
    bool fixed = d > 0.f;   // sign(depth) is 0/1 (depth >= 0)
    float* wp = wts + (((size_t)b * 9) << 16) + hw;
#pragma unroll
    for (int j = 0; j < 9; j++) {
        float v;
        if (j == 4) v = fixed ? 1.f : 0.f;            // center
        else        v = fixed ? 0.f : g[j - (j > 4 ? 1 : 0)] * inv;
        wp[(size_t)j << 16] = v;
    }
}

__device__ __forceinline__ float4 zero4() { return make_float4(0.f, 0.f, 0.f, 0.f); }

__device__ __forceinline__ float4 ldxrow(const float* xc, int row, int w0) {
    if (row < 0 || row >= H_) return zero4();
    return *reinterpret_cast<const float4*>(xc + (size_t)row * W_ + w0);
}

// acc[k] += wgt[3i+j][k] * rb[i][k+j]  — same fmaf order as R3..R14 (passed).
__device__ __forceinline__ void stencil4(const float wgt[9][4],
                                         const float rb[3][6],
                                         float acc[4]) {
#pragma unroll
    for (int i = 0; i < 3; ++i)
#pragma unroll
        for (int j = 0; j < 3; ++j)
#pragma unroll
            for (int k = 0; k < 4; ++k)
                acc[k] = fmaf(wgt[i * 3 + j][k], rb[i][k + j], acc[k]);
}

__device__ __forceinline__ void mkrb(float4 v, bool hasL, bool hasR, float rbrow[6]) {
    float lh = __shfl_up(v.w, 1);
    float rh = __shfl_down(v.x, 1);
    rbrow[0] = hasL ? lh : 0.f;
    rbrow[1] = v.x; rbrow[2] = v.y; rbrow[3] = v.z; rbrow[4] = v.w;
    rbrow[5] = hasR ? rh : 0.f;
}

// Block (64,4): wave s == pipeline stage s (step s+1). One wave = one full
// 256-wide row (64 lanes x 4 px), shfl halos. Rings: 4-row ring per step.
__global__ __launch_bounds__(256)
void prop_stream_kernel(const float* __restrict__ xin,
                        const float* __restrict__ wts,
                        float* __restrict__ xout) {
    __shared__ float ring[T_ - 1][4][CPB][W_];   // 3*4*2*256*4B = 24 KB
    const int tx = threadIdx.x;    // 0..63
    const int s  = threadIdx.y;    // 0..T_-1 (pipeline stage)
    const int h0 = blockIdx.x * CHUNK;
    const int c0 = blockIdx.y * CPB;
    const int b  = blockIdx.z;
    const int w0 = tx * 4;
    const size_t plane = (size_t)H_ * W_;
    const bool hasL = (tx > 0), hasR = (tx < 63);
    const int f_start = h0 - (T_ - 1);
    const int vfront  = f_start + 3 * s;   // first front with valid inputs

    const float* xb = xin + ((size_t)b * C_ + c0) * plane;
    const float* wb = wts + (size_t)b * 9 * plane;

    // stage-0 x register window: rows q-1, q, q+1 (q = f for s=0)
    float4 xm[CPB], xc[CPB], xp[CPB];
    if (s == 0) {
#pragma unroll
        for (int c = 0; c < CPB; ++c) {
            xm[c] = ldxrow(xb + c * plane, f_start - 1, w0);
            xc[c] = ldxrow(xb + c * plane, f_start,     w0);
            xp[c] = ldxrow(xb + c * plane, f_start + 1, w0);
        }
    }

    // prefetch weights for the first front (row clamped; unused when !val)
    float wgt[9][4];
    {
        int q0 = f_start - 2 * s;
        int qc = min(max(q0, 0), H_ - 1);
        const float* wp = wb + (size_t)qc * W_ + w0;
#pragma unroll
        for (int j = 0; j < 9; ++j) {
            float4 v = *reinterpret_cast<const float4*>(wp + j * plane);
            wgt[j][0] = v.x; wgt[j][1] = v.y; wgt[j][2] = v.z; wgt[j][3] = v.w;
        }
    }

    for (int f = f_start; f < f_start + NFRONT; ++f) {
        const int q = f - 2 * s;                 // row this wave produces
        const bool rowok = (q >= 0) && (q < H_);
        const bool val = rowok && (f >= vfront); // inputs fully valid

        // ---- issue next-front prefetches FIRST (max load->use distance) ----
        float wgtn[9][4];
        {
            int qn = min(max(q + 1, 0), H_ - 1);
            const float* wp = wb + (size_t)qn * W_ + w0;
#pragma unroll
            for (int j = 0; j < 9; ++j) {
                float4 v = *reinterpret_cast<const float4*>(wp + j * plane);
                wgtn[j][0] = v.x; wgtn[j][1] = v.y; wgtn[j][2] = v.z; wgtn[j][3] = v.w;
            }
        }
        float4 xnew[CPB];
        if (s == 0) {
#pragma unroll
            for (int c = 0; c < CPB; ++c)
                xnew[c] = ldxrow(xb + c * plane, q + 2, w0);
        }

        // ---- compute current front with wgt (prefetched last iter) ----
        if (s == 0) {
#pragma unroll
            for (int c = 0; c < CPB; ++c) {
                float acc[4] = {0.f, 0.f, 0.f, 0.f};
                if (val) {
                    float rb[3][6];
                    mkrb(xm[c], hasL, hasR, rb[0]);
                    mkrb(xc[c], hasL, hasR, rb[1]);
                    mkrb(xp[c], hasL, hasR, rb[2]);
                    stencil4(wgt, rb, acc);
                }
                *reinterpret_cast<float4*>(&ring[0][q & 3][c][w0]) =
                    make_float4(acc[0], acc[1], acc[2], acc[3]);
            }
#pragma unroll
            for (int c = 0; c < CPB; ++c) {
                xm[c] = xc[c]; xc[c] = xp[c]; xp[c] = xnew[c];
            }
        } else {
#pragma unroll
            for (int c = 0; c < CPB; ++c) {
                float acc[4] = {0.f, 0.f, 0.f, 0.f};
                if (val) {
                    float rb[3][6];
#pragma unroll
                    for (int i = 0; i < 3; ++i) {
                        int p = q - 1 + i;
                        float4 v = (p >= 0 && p < H_)
                            ? *reinterpret_cast<const float4*>(&ring[s - 1][p & 3][c][w0])
                            : zero4();
                        mkrb(v, hasL, hasR, rb[i]);
                    }
                    stencil4(wgt, rb, acc);
                }
                if (s < T_ - 1) {
                    *reinterpret_cast<float4*>(&ring[s][q & 3][c][w0]) =
                        make_float4(acc[0], acc[1], acc[2], acc[3]);
                } else if (val && q >= h0 && q < h0 + CHUNK) {
                    *reinterpret_cast<float4*>(xout + ((size_t)b * C_ + (c0 + c)) * plane +
                                               (size_t)q * W_ + w0) =
                        make_float4(acc[0], acc[1], acc[2], acc[3]);
                }
            }
        }

        __syncthreads();   // front advance: ring writes visible to next front
#pragma unroll
        for (int j = 0; j < 9; ++j) {
            wgt[j][0] = wgtn[j][0]; wgt[j][1] = wgtn[j][1];
            wgt[j][2] = wgtn[j][2]; wgt[j][3] = wgtn[j][3];
        }
    }
}

extern "C" void kernel_launch(void* const* d_in, const int* in_sizes, int n_in,
                              void* d_out, int out_size, void* d_ws, size_t ws_size,
                              hipStream_t stream) {
    const float* x      = (const float*)d_in[0];
    const float* guided = (const float*)d_in[1];
    const float* depth  = (const float*)d_in[2];
    // d_in[3] = prop_time; fixed to 16 by setup_inputs.
    const int DISPATCHES = 4;    // 16 steps, T_=4 per dispatch

    float* xbuf = (float*)d_ws;                                   // 64 MB
    float* wts  = (float*)((char*)d_ws +
                           (size_t)B_ * C_ * H_ * W_ * sizeof(float)); // 18.9 MB
    float* out  = (float*)d_out;

    int total = B_ * H_ * W_;
    hipLaunchKernelGGL(prep_weights_kernel, dim3((total + 255) / 256), dim3(256),
                       0, stream, guided, depth, wts, total);

    dim3 grid(H_ / CHUNK, C_ / CPB, B_), block(64, T_, 1);
    const float* src = x;
    for (int t = 0; t < DISPATCHES; ++t) {
        float* dst = (t == DISPATCHES - 1) ? out : ((t % 2 == 0) ? xbuf : out);
        hipLaunchKernelGGL(prop_stream_kernel, grid, block, 0, stream,
                           src, wts, dst);
        src = dst;
    }
}

// Round 18
// 347.380 us; speedup vs baseline: 1.1878x; 1.1878x over previous
//
#include <hip/hip_runtime.h>

// AffinityPropagate (CSPN): B=8, C=32, H=W=256, K=3, prop_time=16.
// R16: R14 config (T=4, CPB=4, CHUNK=32) + 2-front-deep weight prefetch.
// Three named 36-reg weight buffers rotated by a manual 3-unroll of the
// front loop (no runtime indexing -> no scratch). At front f: use w(f),
// issue w(f+2). Load->use distance = 2 fronts (~600cy) covers L2/LLC.
// NFRONT 41->42 (multiple of 3); the extra front only writes dead ring
// slots (output write guarded). Pad dropped (R14: no effect).

#define B_ 8
#define C_ 32
#define H_ 256
#define W_ 256
#define T_ 4
#define CPB 4
#define CHUNK 32
#define NFRONT 42   // ceil((CHUNK + 3*(T_-1))/3)*3 = 42 fronts

// Planar weights: wts[((b*9)+j)*H*W + h*W + w]
__global__ __launch_bounds__(256)
void prep_weights_kernel(const float* __restrict__ guided,
                         const float* __restrict__ depth,
                         float* __restrict__ wts,
                         int total /* B*H*W */) {
    int idx = blockIdx.x * 256 + threadIdx.x;
    if (idx >= total) return;
    int b  = idx >> 16;        // H*W = 65536
    int hw = idx & 0xFFFF;
    const float* gp = guided + (((size_t)b * 8) << 16) + hw;
    float g[8];
    float m = -3.4e38f;
#pragma unroll
    for (int j = 0; j < 8; j++) { g[j] = gp[(size_t)j << 16]; m = fmaxf(m, g[j]); }
    float s = 0.f;
#pragma unroll
    for (int j = 0; j < 8; j++) { g[j] = expf(g[j] - m); s += g[j]; }
    float inv = 1.0f / s;
    float d = depth[(((size_t)b) << 16) + hw];
    bool fixed = d > 0.f;   // sign(depth) is 0/1 (depth >= 0)
    float* wp = wts + (((size_t)b * 9) << 16) + hw;
#pragma unroll
    for (int j = 0; j < 9; j++) {
        float v;
        if (j == 4) v = fixed ? 1.f : 0.f;            // center
        else        v = fixed ? 0.f : g[j - (j > 4 ? 1 : 0)] * inv;
        wp[(size_t)j << 16] = v;
    }
}

__device__ __forceinline__ float4 zero4() { return make_float4(0.f, 0.f, 0.f, 0.f); }

__device__ __forceinline__ float4 ldxrow(const float* xc, int row, int w0) {
    if (row < 0 || row >= H_) return zero4();
    return *reinterpret_cast<const float4*>(xc + (size_t)row * W_ + w0);
}

// acc[k] += wgt[3i+j][k] * rb[i][k+j]  — same fmaf order as R3..R15 (passed).
__device__ __forceinline__ void stencil4(const float wgt[9][4],
                                         const float rb[3][6],
                                         float acc[4]) {
#pragma unroll
    for (int i = 0; i < 3; ++i)
#pragma unroll
        for (int j = 0; j < 3; ++j)
#pragma unroll
            for (int k = 0; k < 4; ++k)
                acc[k] = fmaf(wgt[i * 3 + j][k], rb[i][k + j], acc[k]);
}

__device__ __forceinline__ void mkrb(float4 v, bool hasL, bool hasR, float rbrow[6]) {
    float lh = __shfl_up(v.w, 1);
    float rh = __shfl_down(v.x, 1);
    rbrow[0] = hasL ? lh : 0.f;
    rbrow[1] = v.x; rbrow[2] = v.y; rbrow[3] = v.z; rbrow[4] = v.w;
    rbrow[5] = hasR ? rh : 0.f;
}

__device__ __forceinline__ void load_wrow(const float* wb, int row, int w0,
                                          size_t plane, float (&w)[9][4]) {
    int qc = min(max(row, 0), H_ - 1);   // clamp; value unused when invalid
    const float* wp = wb + (size_t)qc * W_ + w0;
#pragma unroll
    for (int j = 0; j < 9; ++j) {
        float4 v = *reinterpret_cast<const float4*>(wp + j * plane);
        w[j][0] = v.x; w[j][1] = v.y; w[j][2] = v.z; w[j][3] = v.w;
    }
}

// Block (64,4): wave s == pipeline stage s (step s+1). One wave = one full
// 256-wide row (64 lanes x 4 px), shfl halos. Rings: 4-row ring per step.
__global__ __launch_bounds__(256)
void prop_stream_kernel(const float* __restrict__ xin,
                        const float* __restrict__ wts,
                        float* __restrict__ xout) {
    __shared__ float ring[T_ - 1][4][CPB][W_];   // 48 KB
    const int tx = threadIdx.x;    // 0..63
    const int s  = threadIdx.y;    // 0..T_-1 (pipeline stage)
    const int h0 = blockIdx.x * CHUNK;
    const int c0 = blockIdx.y * CPB;
    const int b  = blockIdx.z;
    const int w0 = tx * 4;
    const size_t plane = (size_t)H_ * W_;
    const bool hasL = (tx > 0), hasR = (tx < 63);
    const int f_start = h0 - (T_ - 1);
    const int vfront  = f_start + 3 * s;   // first front with valid inputs

    const float* xb = xin + ((size_t)b * C_ + c0) * plane;
    const float* wb = wts + (size_t)b * 9 * plane;
    float*       ob = xout + ((size_t)b * C_ + c0) * plane;

    // stage-0 x register window: rows q-1, q, q+1 (q = f for s=0)
    float4 xm[CPB], xc[CPB], xp[CPB];
    if (s == 0) {
#pragma unroll
        for (int c = 0; c < CPB; ++c) {
            xm[c] = ldxrow(xb + c * plane, f_start - 1, w0);
            xc[c] = ldxrow(xb + c * plane, f_start,     w0);
            xp[c] = ldxrow(xb + c * plane, f_start + 1, w0);
        }
    }

    // 2-deep weight pipeline: wA=front f_start, wB=f_start+1, wC issued in loop
    float wA[9][4], wB[9][4], wC[9][4];
    load_wrow(wb, f_start - 2 * s,     w0, plane, wA);
    load_wrow(wb, f_start + 1 - 2 * s, w0, plane, wB);

    auto front_step = [&](int f, float (&wuse)[9][4], float (&wiss)[9][4]) {
        const int q = f - 2 * s;                 // row this wave produces
        const bool rowok = (q >= 0) && (q < H_);
        const bool val = rowok && (f >= vfront); // inputs fully valid

        // issue weights for front f+2 (this wave's row q+2) — 2-front distance
        load_wrow(wb, q + 2, w0, plane, wiss);
        // issue next x row (stage 0)
        float4 xnew[CPB];
        if (s == 0) {
#pragma unroll
            for (int c = 0; c < CPB; ++c)
                xnew[c] = ldxrow(xb + c * plane, q + 2, w0);
        }

        if (s == 0) {
#pragma unroll
            for (int c = 0; c < CPB; ++c) {
                float acc[4] = {0.f, 0.f, 0.f, 0.f};
                if (val) {
                    float rb[3][6];
                    mkrb(xm[c], hasL, hasR, rb[0]);
                    mkrb(xc[c], hasL, hasR, rb[1]);
                    mkrb(xp[c], hasL, hasR, rb[2]);
                    stencil4(wuse, rb, acc);
                }
                *reinterpret_cast<float4*>(&ring[0][q & 3][c][w0]) =
                    make_float4(acc[0], acc[1], acc[2], acc[3]);
            }
#pragma unroll
            for (int c = 0; c < CPB; ++c) {
                xm[c] = xc[c]; xc[c] = xp[c]; xp[c] = xnew[c];
            }
        } else {
#pragma unroll
            for (int c = 0; c < CPB; ++c) {
                float acc[4] = {0.f, 0.f, 0.f, 0.f};
                if (val) {
                    float rb[3][6];
#pragma unroll
                    for (int i = 0; i < 3; ++i) {
                        int p = q - 1 + i;
                        float4 v = (p >= 0 && p < H_)
                            ? *reinterpret_cast<const float4*>(&ring[s - 1][p & 3][c][w0])
                            : zero4();
                        mkrb(v, hasL, hasR, rb[i]);
                    }
                    stencil4(wuse, rb, acc);
                }
                if (s < T_ - 1) {
                    *reinterpret_cast<float4*>(&ring[s][q & 3][c][w0]) =
                        make_float4(acc[0], acc[1], acc[2], acc[3]);
                } else if (val && q >= h0 && q < h0 + CHUNK) {
                    *reinterpret_cast<float4*>(ob + (size_t)c * plane +
                                               (size_t)q * W_ + w0) =
                        make_float4(acc[0], acc[1], acc[2], acc[3]);
                }
            }
        }
        __syncthreads();   // front advance: ring writes visible to next front
    };

    // manual 3-unroll rotates the three weight buffers by NAME (no runtime
    // indexing -> no scratch). Front n uses buffer issued at front n-2.
    for (int ff = 0; ff < NFRONT; ff += 3) {
        front_step(f_start + ff + 0, wA, wC);
        front_step(f_start + ff + 1, wB, wA);
        front_step(f_start + ff + 2, wC, wB);
    }
}

extern "C" void kernel_launch(void* const* d_in, const int* in_sizes, int n_in,
                              void* d_out, int out_size, void* d_ws, size_t ws_size,
                              hipStream_t stream) {
    const float* x      = (const float*)d_in[0];
    const float* guided = (const float*)d_in[1];
    const float* depth  = (const float*)d_in[2];
    // d_in[3] = prop_time; fixed to 16 by setup_inputs.
    const int DISPATCHES = 4;    // 16 steps, T_=4 per dispatch

    float* xbuf = (float*)d_ws;                                   // 64 MB
    float* wts  = (float*)((char*)d_ws +
                           (size_t)B_ * C_ * H_ * W_ * sizeof(float)); // 18.9 MB
    float* out  = (float*)d_out;

    int total = B_ * H_ * W_;
    hipLaunchKernelGGL(prep_weights_kernel, dim3((total + 255) / 256), dim3(256),
                       0, stream, guided, depth, wts, total);

    dim3 grid(H_ / CHUNK, C_ / CPB, B_), block(64, T_, 1);
    const float* src = x;
    for (int t = 0; t < DISPATCHES; ++t) {
        float* dst = (t == DISPATCHES - 1) ? out : ((t % 2 == 0) ? xbuf : out);
        hipLaunchKernelGGL(prop_stream_kernel, grid, block, 0, stream,
                           src, wts, dst);
        src = dst;
    }
}

// Round 21
// 345.041 us; speedup vs baseline: 1.1959x; 1.0068x over previous
//
#include <hip/hip_runtime.h>

// AffinityPropagate (CSPN): B=8, C=32, H=W=256, K=3, prop_time=16.
// R18: R16 (T=4, CPB=4, 2-front-deep named weight pipeline) + RELAXED
// front barrier. __syncthreads() emits s_waitcnt vmcnt(0) lgkmcnt(0) which
// drained the prefetched global loads every front (defeating R14/R16's
// pipelines). Replaced with lgkmcnt(0)-only wait + raw s_barrier: LDS ring
// ordering preserved, weight/x loads stay in flight across fronts.

#define B_ 8
#define C_ 32
#define H_ 256
#define W_ 256
#define T_ 4
#define CPB 4
#define CHUNK 32
#define NFRONT 42   // multiple of 3 for the named-buffer rotation

// Planar weights: wts[((b*9)+j)*H*W + h*W + w]
__global__ __launch_bounds__(256)
void prep_weights_kernel(const float* __restrict__ guided,
                         const float* __restrict__ depth,
                         float* __restrict__ wts,
                         int total /* B*H*W */) {
    int idx = blockIdx.x * 256 + threadIdx.x;
    if (idx >= total) return;
    int b  = idx >> 16;        // H*W = 65536
    int hw = idx & 0xFFFF;
    const float* gp = guided + (((size_t)b * 8) << 16) + hw;
    float g[8];
    float m = -3.4e38f;
#pragma unroll
    for (int j = 0; j < 8; j++) { g[j] = gp[(size_t)j << 16]; m = fmaxf(m, g[j]); }
    float s = 0.f;
#pragma unroll
    for (int j = 0; j < 8; j++) { g[j] = expf(g[j] - m); s += g[j]; }
    float inv = 1.0f / s;
    float d = depth[(((size_t)b) << 16) + hw];
    bool fixed = d > 0.f;   // sign(depth) is 0/1 (depth >= 0)
    float* wp = wts + (((size_t)b * 9) << 16) + hw;
#pragma unroll
    for (int j = 0; j < 9; j++) {
        float v;
        if (j == 4) v = fixed ? 1.f : 0.f;            // center
        else        v = fixed ? 0.f : g[j - (j > 4 ? 1 : 0)] * inv;
        wp[(size_t)j << 16] = v;
    }
}

__device__ __forceinline__ float4 zero4() { return make_float4(0.f, 0.f, 0.f, 0.f); }

__device__ __forceinline__ float4 ldxrow(const float* xc, int row, int w0) {
    if (row < 0 || row >= H_) return zero4();
    return *reinterpret_cast<const float4*>(xc + (size_t)row * W_ + w0);
}

// acc[k] += wgt[3i+j][k] * rb[i][k+j]  — same fmaf order as R3..R16 (passed).
__device__ __forceinline__ void stencil4(const float wgt[9][4],
                                         const float rb[3][6],
                                         float acc[4]) {
#pragma unroll
    for (int i = 0; i < 3; ++i)
#pragma unroll
        for (int j = 0; j < 3; ++j)
#pragma unroll
            for (int k = 0; k < 4; ++k)
                acc[k] = fmaf(wgt[i * 3 + j][k], rb[i][k + j], acc[k]);
}

__device__ __forceinline__ void mkrb(float4 v, bool hasL, bool hasR, float rbrow[6]) {
    float lh = __shfl_up(v.w, 1);
    float rh = __shfl_down(v.x, 1);
    rbrow[0] = hasL ? lh : 0.f;
    rbrow[1] = v.x; rbrow[2] = v.y; rbrow[3] = v.z; rbrow[4] = v.w;
    rbrow[5] = hasR ? rh : 0.f;
}

__device__ __forceinline__ void load_wrow(const float* wb, int row, int w0,
                                          size_t plane, float (&w)[9][4]) {
    int qc = min(max(row, 0), H_ - 1);   // clamp; value unused when invalid
    const float* wp = wb + (size_t)qc * W_ + w0;
#pragma unroll
    for (int j = 0; j < 9; ++j) {
        float4 v = *reinterpret_cast<const float4*>(wp + j * plane);
        w[j][0] = v.x; w[j][1] = v.y; w[j][2] = v.z; w[j][3] = v.w;
    }
}

// Relaxed front barrier: drain LDS (ring writes + shfl) only; leave global
// loads (weight/x prefetch) and stores in flight across the barrier.
__device__ __forceinline__ void front_barrier() {
    asm volatile("s_waitcnt lgkmcnt(0)" ::: "memory");
    __builtin_amdgcn_s_barrier();
    __builtin_amdgcn_sched_barrier(0);
}

// Block (64,4): wave s == pipeline stage s (step s+1). One wave = one full
// 256-wide row (64 lanes x 4 px), shfl halos. Rings: 4-row ring per step.
__global__ __launch_bounds__(256)
void prop_stream_kernel(const float* __restrict__ xin,
                        const float* __restrict__ wts,
                        float* __restrict__ xout) {
    __shared__ float ring[T_ - 1][4][CPB][W_];   // 48 KB
    const int tx = threadIdx.x;    // 0..63
    const int s  = threadIdx.y;    // 0..T_-1 (pipeline stage)
    const int h0 = blockIdx.x * CHUNK;
    const int c0 = blockIdx.y * CPB;
    const int b  = blockIdx.z;
    const int w0 = tx * 4;
    const size_t plane = (size_t)H_ * W_;
    const bool hasL = (tx > 0), hasR = (tx < 63);
    const int f_start = h0 - (T_ - 1);
    const int vfront  = f_start + 3 * s;   // first front with valid inputs

    const float* xb = xin + ((size_t)b * C_ + c0) * plane;
    const float* wb = wts + (size_t)b * 9 * plane;
    float*       ob = xout + ((size_t)b * C_ + c0) * plane;

    // stage-0 x register window: rows q-1, q, q+1 (q = f for s=0)
    float4 xm[CPB], xc[CPB], xp[CPB];
    if (s == 0) {
#pragma unroll
        for (int c = 0; c < CPB; ++c) {
            xm[c] = ldxrow(xb + c * plane, f_start - 1, w0);
            xc[c] = ldxrow(xb + c * plane, f_start,     w0);
            xp[c] = ldxrow(xb + c * plane, f_start + 1, w0);
        }
    }

    // 2-deep weight pipeline: wA=front f_start, wB=f_start+1, wC issued in loop
    float wA[9][4], wB[9][4], wC[9][4];
    load_wrow(wb, f_start - 2 * s,     w0, plane, wA);
    load_wrow(wb, f_start + 1 - 2 * s, w0, plane, wB);

    auto front_step = [&](int f, float (&wuse)[9][4], float (&wiss)[9][4]) {
        const int q = f - 2 * s;                 // row this wave produces
        const bool rowok = (q >= 0) && (q < H_);
        const bool val = rowok && (f >= vfront); // inputs fully valid

        // issue weights for front f+2 (this wave's row q+2) — these loads now
        // genuinely stay in flight across the relaxed barriers below
        load_wrow(wb, q + 2, w0, plane, wiss);
        // issue next x row (stage 0)
        float4 xnew[CPB];
        if (s == 0) {
#pragma unroll
            for (int c = 0; c < CPB; ++c)
                xnew[c] = ldxrow(xb + c * plane, q + 2, w0);
        }

        if (s == 0) {
#pragma unroll
            for (int c = 0; c < CPB; ++c) {
                float acc[4] = {0.f, 0.f, 0.f, 0.f};
                if (val) {
                    float rb[3][6];
                    mkrb(xm[c], hasL, hasR, rb[0]);
                    mkrb(xc[c], hasL, hasR, rb[1]);
                    mkrb(xp[c], hasL, hasR, rb[2]);
                    stencil4(wuse, rb, acc);
                }
                *reinterpret_cast<float4*>(&ring[0][q & 3][c][w0]) =
                    make_float4(acc[0], acc[1], acc[2], acc[3]);
            }
#pragma unroll
            for (int c = 0; c < CPB; ++c) {
                xm[c] = xc[c]; xc[c] = xp[c]; xp[c] = xnew[c];
            }
        } else {
#pragma unroll
            for (int c = 0; c < CPB; ++c) {
                float acc[4] = {0.f, 0.f, 0.f, 0.f};
                if (val) {
                    float rb[3][6];
#pragma unroll
                    for (int i = 0; i < 3; ++i) {
                        int p = q - 1 + i;
                        float4 v = (p >= 0 && p < H_)
                            ? *reinterpret_cast<const float4*>(&ring[s - 1][p & 3][c][w0])
                            : zero4();
                        mkrb(v, hasL, hasR, rb[i]);
                    }
                    stencil4(wuse, rb, acc);
                }
                if (s < T_ - 1) {
                    *reinterpret_cast<float4*>(&ring[s][q & 3][c][w0]) =
                        make_float4(acc[0], acc[1], acc[2], acc[3]);
                } else if (val && q >= h0 && q < h0 + CHUNK) {
                    *reinterpret_cast<float4*>(ob + (size_t)c * plane +
                                               (size_t)q * W_ + w0) =
                        make_float4(acc[0], acc[1], acc[2], acc[3]);
                }
            }
        }
        front_barrier();   // LDS-only drain; global prefetch stays in flight
    };

    // manual 3-unroll rotates the three weight buffers by NAME (no runtime
    // indexing -> no scratch). Front n uses buffer issued at front n-2.
    for (int ff = 0; ff < NFRONT; ff += 3) {
        front_step(f_start + ff + 0, wA, wC);
        front_step(f_start + ff + 1, wB, wA);
        front_step(f_start + ff + 2, wC, wB);
    }
}

extern "C" void kernel_launch(void* const* d_in, const int* in_sizes, int n_in,
                              void* d_out, int out_size, void* d_ws, size_t ws_size,
                              hipStream_t stream) {
    const float* x      = (const float*)d_in[0];
    const float* guided = (const float*)d_in[1];
    const float* depth  = (const float*)d_in[2];
    // d_in[3] = prop_time; fixed to 16 by setup_inputs.
    const int DISPATCHES = 4;    // 16 steps, T_=4 per dispatch

    float* xbuf = (float*)d_ws;                                   // 64 MB
    float* wts  = (float*)((char*)d_ws +
                           (size_t)B_ * C_ * H_ * W_ * sizeof(float)); // 18.9 MB
    float* out  = (float*)d_out;

    int total = B_ * H_ * W_;
    hipLaunchKernelGGL(prep_weights_kernel, dim3((total + 255) / 256), dim3(256),
                       0, stream, guided, depth, wts, total);

    dim3 grid(H_ / CHUNK, C_ / CPB, B_), block(64, T_, 1);
    const float* src = x;
    for (int t = 0; t < DISPATCHES; ++t) {
        float* dst = (t == DISPATCHES - 1) ? out : ((t % 2 == 0) ? xbuf : out);
        hipLaunchKernelGGL(prop_stream_kernel, grid, block, 0, stream,
                           src, wts, dst);
        src = dst;
    }
}

// Round 22
// 215.102 us; speedup vs baseline: 1.9183x; 1.6041x over previous
//
#include <hip/hip_runtime.h>

// AffinityPropagate (CSPN): B=8, C=32, H=W=256, K=3, prop_time=16.
// R21: wave-autonomous 4-step register pipeline. No LDS, no barriers.
// One wave = one (b, c, 32-row chunk); sweeps down H computing
// s1[f] -> s2[f-1] -> s3[f-2] -> s4[f-3] per front, all state in registers
// (2-row carried window per stage; 4 rotating 36-reg weight buffers rotated
// BY NAME via 4-unrolled loop). Horizontal halos via shfl (wave = full row).
// Removes the 42 serialized LDS-write/barrier/LDS-read round-trips that
// pinned R13-R18 at ~98us regardless of prefetch depth or barrier type.

#define B_ 8
#define C_ 32
#define H_ 256
#define W_ 256
#define CHUNK 32
#define NF 40   // fronts f0..f0+39, f0 = h0-3 (38 needed, rounded to 4)

// Planar weights: wts[((b*9)+j)*H*W + h*W + w]
__global__ __launch_bounds__(256)
void prep_weights_kernel(const float* __restrict__ guided,
                         const float* __restrict__ depth,
                         float* __restrict__ wts,
                         int total /* B*H*W */) {
    int idx = blockIdx.x * 256 + threadIdx.x;
    if (idx >= total) return;
    int b  = idx >> 16;        // H*W = 65536
    int hw = idx & 0xFFFF;
    const float* gp = guided + (((size_t)b * 8) << 16) + hw;
    float g[8];
    float m = -3.4e38f;
#pragma unroll
    for (int j = 0; j < 8; j++) { g[j] = gp[(size_t)j << 16]; m = fmaxf(m, g[j]); }
    float s = 0.f;
#pragma unroll
    for (int j = 0; j < 8; j++) { g[j] = expf(g[j] - m); s += g[j]; }
    float inv = 1.0f / s;
    float d = depth[(((size_t)b) << 16) + hw];
    bool fixed = d > 0.f;   // sign(depth) is 0/1 (depth >= 0)
    float* wp = wts + (((size_t)b * 9) << 16) + hw;
#pragma unroll
    for (int j = 0; j < 9; j++) {
        float v;
        if (j == 4) v = fixed ? 1.f : 0.f;            // center
        else        v = fixed ? 0.f : g[j - (j > 4 ? 1 : 0)] * inv;
        wp[(size_t)j << 16] = v;
    }
}

__device__ __forceinline__ float4 zero4() { return make_float4(0.f, 0.f, 0.f, 0.f); }

__device__ __forceinline__ float4 ldxrow(const float* xc, int row, int w0) {
    if (row < 0 || row >= H_) return zero4();
    return *reinterpret_cast<const float4*>(xc + (size_t)row * W_ + w0);
}

// acc[k] += wgt[3i+j][k] * rb[i][k+j]  — same fmaf order as R3..R18 (passed).
__device__ __forceinline__ void stencil4(const float wgt[9][4],
                                         const float rb[3][6],
                                         float acc[4]) {
#pragma unroll
    for (int i = 0; i < 3; ++i)
#pragma unroll
        for (int j = 0; j < 3; ++j)
#pragma unroll
            for (int k = 0; k < 4; ++k)
                acc[k] = fmaf(wgt[i * 3 + j][k], rb[i][k + j], acc[k]);
}

__device__ __forceinline__ void mkrb(float4 v, bool hasL, bool hasR, float rbrow[6]) {
    float lh = __shfl_up(v.w, 1);
    float rh = __shfl_down(v.x, 1);
    rbrow[0] = hasL ? lh : 0.f;
    rbrow[1] = v.x; rbrow[2] = v.y; rbrow[3] = v.z; rbrow[4] = v.w;
    rbrow[5] = hasR ? rh : 0.f;
}

__device__ __forceinline__ void load_wrow(const float* wb, int row, int w0,
                                          size_t plane, float (&w)[9][4]) {
    int qc = min(max(row, 0), H_ - 1);   // clamp; guarded consumers ignore
    const float* wp = wb + (size_t)qc * W_ + w0;
#pragma unroll
    for (int j = 0; j < 9; ++j) {
        float4 v = *reinterpret_cast<const float4*>(wp + j * plane);
        w[j][0] = v.x; w[j][1] = v.y; w[j][2] = v.z; w[j][3] = v.w;
    }
}

// One wave per block (64 lanes x 4 px = full 256-wide row).
__global__ __launch_bounds__(64, 2)
void prop_wave_kernel(const float* __restrict__ xin,
                      const float* __restrict__ wts,
                      float* __restrict__ xout) {
    const int tx = threadIdx.x;            // 0..63
    const int h0 = blockIdx.x * CHUNK;
    const int c  = blockIdx.y;
    const int b  = blockIdx.z;
    const int w0 = tx * 4;
    const size_t plane = (size_t)H_ * W_;
    const bool hasL = (tx > 0), hasR = (tx < 63);
    const int f0 = h0 - 3;

    const float* xc = xin + ((size_t)b * C_ + c) * plane;
    const float* wb = wts + (size_t)b * 9 * plane;
    float*       oc = xout + ((size_t)b * C_ + c) * plane;

    // x window: rows f-1, f, f+1
    float4 xm = ldxrow(xc, f0 - 1, w0);
    float4 xq = ldxrow(xc, f0,     w0);
    float4 xp = ldxrow(xc, f0 + 1, w0);
    // carried 2-row windows per stage (zero-init feeds only guarded rows)
    float4 s1a = zero4(), s1b = zero4();   // s1[f-2], s1[f-1]
    float4 s2a = zero4(), s2b = zero4();   // s2[f-3], s2[f-2]
    float4 s3a = zero4(), s3b = zero4();   // s3[f-4], s3[f-3]
    // 4 rotating weight-row buffers: rows f, f-1, f-2, f-3
    float wg0[9][4], wg1[9][4], wg2[9][4], wg3[9][4];
    load_wrow(wb, f0,     w0, plane, wg0);
    load_wrow(wb, f0 - 1, w0, plane, wg1);
    load_wrow(wb, f0 - 2, w0, plane, wg2);
    load_wrow(wb, f0 - 3, w0, plane, wg3);

    auto front = [&](int f, const float (&w1)[9][4], const float (&w2)[9][4],
                     const float (&w3)[9][4], float (&w4)[9][4]) {
        // s1[f]
        float4 n1 = zero4();
        if (f >= 0 && f < H_) {
            float rb[3][6];
            mkrb(xm, hasL, hasR, rb[0]);
            mkrb(xq, hasL, hasR, rb[1]);
            mkrb(xp, hasL, hasR, rb[2]);
            float acc[4] = {0.f, 0.f, 0.f, 0.f};
            stencil4(w1, rb, acc);
            n1 = make_float4(acc[0], acc[1], acc[2], acc[3]);
        }
        // s2[f-1]
        float4 n2 = zero4();
        if (f - 1 >= 0 && f - 1 < H_) {
            float rb[3][6];
            mkrb(s1a, hasL, hasR, rb[0]);
            mkrb(s1b, hasL, hasR, rb[1]);
            mkrb(n1,  hasL, hasR, rb[2]);
            float acc[4] = {0.f, 0.f, 0.f, 0.f};
            stencil4(w2, rb, acc);
            n2 = make_float4(acc[0], acc[1], acc[2], acc[3]);
        }
        // s3[f-2]
        float4 n3 = zero4();
        if (f - 2 >= 0 && f - 2 < H_) {
            float rb[3][6];
            mkrb(s2a, hasL, hasR, rb[0]);
            mkrb(s2b, hasL, hasR, rb[1]);
            mkrb(n2,  hasL, hasR, rb[2]);
            float acc[4] = {0.f, 0.f, 0.f, 0.f};
            stencil4(w3, rb, acc);
            n3 = make_float4(acc[0], acc[1], acc[2], acc[3]);
        }
        // s4[f-3] -> store (consumes w4, freeing it for the reload below)
        const int q = f - 3;
        if (q >= h0 && q < h0 + CHUNK) {
            float rb[3][6];
            mkrb(s3a, hasL, hasR, rb[0]);
            mkrb(s3b, hasL, hasR, rb[1]);
            mkrb(n3,  hasL, hasR, rb[2]);
            float acc[4] = {0.f, 0.f, 0.f, 0.f};
            stencil4(w4, rb, acc);
            *reinterpret_cast<float4*>(oc + (size_t)q * W_ + w0) =
                make_float4(acc[0], acc[1], acc[2], acc[3]);
        }
        // reload w4 with row f+1 (next front's s1 weights); prefetch x[f+2]
        load_wrow(wb, f + 1, w0, plane, w4);
        float4 xn = ldxrow(xc, f + 2, w0);
        // rotate data windows
        xm = xq; xq = xp; xp = xn;
        s1a = s1b; s1b = n1;
        s2a = s2b; s2b = n2;
        s3a = s3b; s3b = n3;
    };

    // 4-unroll rotates weight buffers by NAME (no runtime indexing).
    for (int u = 0; u < NF; u += 4) {
        front(f0 + u + 0, wg0, wg1, wg2, wg3);   // loads f0+u+1 -> wg3
        front(f0 + u + 1, wg3, wg0, wg1, wg2);   // loads f0+u+2 -> wg2
        front(f0 + u + 2, wg2, wg3, wg0, wg1);   // loads f0+u+3 -> wg1
        front(f0 + u + 3, wg1, wg2, wg3, wg0);   // loads f0+u+4 -> wg0
    }
}

extern "C" void kernel_launch(void* const* d_in, const int* in_sizes, int n_in,
                              void* d_out, int out_size, void* d_ws, size_t ws_size,
                              hipStream_t stream) {
    const float* x      = (const float*)d_in[0];
    const float* guided = (const float*)d_in[1];
    const float* depth  = (const float*)d_in[2];
    // d_in[3] = prop_time; fixed to 16 by setup_inputs.
    const int DISPATCHES = 4;    // 16 steps, 4 per dispatch

    float* xbuf = (float*)d_ws;                                   // 64 MB
    float* wts  = (float*)((char*)d_ws +
                           (size_t)B_ * C_ * H_ * W_ * sizeof(float)); // 18.9 MB
    float* out  = (float*)d_out;

    int total = B_ * H_ * W_;
    hipLaunchKernelGGL(prep_weights_kernel, dim3((total + 255) / 256), dim3(256),
                       0, stream, guided, depth, wts, total);

    dim3 grid(H_ / CHUNK, C_, B_), block(64, 1, 1);   // 2048 x 1-wave blocks
    const float* src = x;
    for (int t = 0; t < DISPATCHES; ++t) {
        float* dst = (t == DISPATCHES - 1) ? out : ((t % 2 == 0) ? xbuf : out);
        hipLaunchKernelGGL(prop_wave_kernel, grid, block, 0, stream,
                           src, wts, dst);
        src = dst;
    }
}